// Round 12
// baseline (23.522 us; speedup 1.0000x reference)
//
#include <hip/hip_runtime.h>
#include <float.h>
#include <math.h>

#define BB 8
#define PP 4096

typedef __attribute__((ext_vector_type(8))) short bf16x8;
typedef __attribute__((ext_vector_type(16))) float f32x16;

__device__ __forceinline__ unsigned int f2bf(float f) {
    unsigned int u = __float_as_uint(f);
    return (u + 0x7FFFu + ((u >> 16) & 1u)) >> 16;   // RNE bf16
}
__device__ __forceinline__ float bf2f(unsigned int h) {
    return __uint_as_float(h << 16);
}
__device__ __forceinline__ float min3f(float a, float b, float c) {
    return fminf(fminf(a, b), c);                    // fuses to v_min3_f32
}

// Prebuild: A-frags for all 16 (dir,cloud) sets -> ws. Layout per set:
// [half][jtile 0..63][64 x uint4]  (32 lof rows + 32 hif rows), 128 KB/set.
// A lane<32 (k0..7):  [chix,chiy,chiz, chix,chiy,chiz, clox,cloy]
// A lane>=32 (k8..15):[cloz, h_hi, h_lo, 0,0,0,0,0]
__global__ __launch_bounds__(256) void build_frags(
    const float* __restrict__ y1, const float* __restrict__ y2,
    uint4* __restrict__ frags)
{
    const int gid   = blockIdx.x * 256 + threadIdx.x;  // 0..65535
    const int cs    = gid >> 12;                       // dir*8 + cloud
    const int n     = gid & 4095;                      // neighbor in cloud
    const int dir   = cs >> 3;
    const int cloud = cs & 7;
    const float* tgt = (dir == 0) ? y2 : y1;
    const float* g = tgt + ((size_t)cloud * PP + n) * 3;

    const float cx = g[0], cy = g[1], cz = g[2];
    const unsigned int chx = f2bf(cx), chy = f2bf(cy), chz = f2bf(cz);
    const unsigned int clx = f2bf(cx - bf2f(chx));
    const unsigned int cly = f2bf(cy - bf2f(chy));
    const unsigned int clz = f2bf(cz - bf2f(chz));
    const float hh = 0.5f * (cx * cx + cy * cy + cz * cz);
    const unsigned int hhi = f2bf(hh);
    const unsigned int hlo = f2bf(hh - bf2f(hhi));

    uint4 lof, hif;
    lof.x = chx | (chy << 16);
    lof.y = chz | (chx << 16);
    lof.z = chy | (chz << 16);
    lof.w = clx | (cly << 16);
    hif.x = clz | (hhi << 16);
    hif.y = hlo;
    hif.z = 0u;
    hif.w = 0u;

    const int half = n >> 11, nl = n & 2047, tile = nl >> 5, r = nl & 31;
    uint4* dst = frags + ((size_t)cs * 8192 + (size_t)half * 4096 + (size_t)tile * 64);
    dst[r]      = lof;
    dst[32 + r] = hif;
}

// One block = (dir, cloud, qgroup of 256 queries) vs all 4096 neighbors.
// MFMA computes t_ji = h_j - a_i.c_j (split-precision bf16 packed into K);
// d^2 = |a|^2 + 2*min_j t.  D[j,i]: col=lane&31 (query), rows over regs/lane-half.
// A-frags are PREBUILT; staging is a linear global_load_lds copy (no VALU).
__global__ __launch_bounds__(1024) void chamfer_mfma(
    const float* __restrict__ y1, const float* __restrict__ y2,
    const uint4* __restrict__ frags, float* __restrict__ partial)
{
    __shared__ uint4 fbuf[64 * 64];   // 64 KB: A-frags for 64 jtiles (half cloud)

    const int bid   = blockIdx.x;
    const int qg    = bid & 15;
    const int cloud = (bid >> 4) & 7;
    const int dir   = bid >> 7;
    const int cs    = bid >> 4;       // dir*8 + cloud

    const float* src = (dir == 0) ? y1 : y2;
    const float* __restrict__ src_base = src + ((size_t)cloud * PP + (size_t)qg * 256) * 3;

    const int tid  = threadIdx.x;
    const int lane = tid & 63;
    const int w    = tid >> 6;
    const int ig   = w & 7;     // itile (32 queries) this wave owns
    const int jh   = w >> 3;    // which 32-jtile half-range this wave owns

    // ---- B-frag (queries), built once in registers ----
    // lane<32 (k0..7):  [nahix,nahiy,nahiz, nalox,naloy,naloz, nahix,nahiy]
    // lane>=32 (k8..15):[nahiz, 1.0, 1.0, 0,0,0,0,0]
    bf16x8 bfrag;
    {
        const int ql = ig * 32 + (lane & 31);
        const float ax = src_base[ql * 3 + 0];
        const float ay = src_base[ql * 3 + 1];
        const float az = src_base[ql * 3 + 2];
        const unsigned int hx = f2bf(-ax), hy = f2bf(-ay), hz = f2bf(-az);
        const unsigned int lx = f2bf(-ax - bf2f(hx));
        const unsigned int ly = f2bf(-ay - bf2f(hy));
        const unsigned int lz = f2bf(-az - bf2f(hz));
        uint4 bb;
        if (lane < 32) {
            bb.x = hx | (hy << 16);
            bb.y = hz | (lx << 16);
            bb.z = ly | (lz << 16);
            bb.w = hx | (hy << 16);
        } else {
            bb.x = hz | (0x3F80u << 16);   // k8 = nahiz, k9 = 1.0
            bb.y = 0x3F80u;                // k10 = 1.0, k11 = 0
            bb.z = 0u;
            bb.w = 0u;
        }
        bfrag = *reinterpret_cast<bf16x8*>(&bb);
    }

    float m0 = FLT_MAX, m1 = FLT_MAX, m2 = FLT_MAX, m3 = FLT_MAX;

    f32x16 zc;
    #pragma unroll
    for (int r = 0; r < 16; ++r) zc[r] = 0.0f;

#define FOLD(acc)                              \
    do {                                       \
        m0 = min3f(m0, (acc)[0], (acc)[4]);    \
        m1 = min3f(m1, (acc)[1], (acc)[5]);    \
        m2 = min3f(m2, (acc)[2], (acc)[6]);    \
        m3 = min3f(m3, (acc)[3], (acc)[7]);    \
        m0 = min3f(m0, (acc)[8], (acc)[12]);   \
        m1 = min3f(m1, (acc)[9], (acc)[13]);   \
        m2 = min3f(m2, (acc)[10], (acc)[14]);  \
        m3 = min3f(m3, (acc)[11], (acc)[15]);  \
    } while (0)

    for (int half = 0; half < 2; ++half) {
        // ---- Stage 64 KB of prebuilt frags: pure linear global_load_lds copy ----
        const uint4* __restrict__ gsrc = frags + ((size_t)cs * 8192 + (size_t)half * 4096);
        #pragma unroll
        for (int r = 0; r < 4; ++r) {
            const int chunk = r * 16 + w;                 // 64 chunks of 1 KB
            const uint4* gp = gsrc + chunk * 64 + lane;   // per-lane global addr
            uint4* lp = &fbuf[chunk * 64];                // wave-uniform LDS base
            __builtin_amdgcn_global_load_lds(
                (const __attribute__((address_space(1))) uint4*)gp,
                (__attribute__((address_space(3))) uint4*)lp, 16, 0, 0);
        }
        __syncthreads();   // compiler emits vmcnt(0) drain before barrier

        // ---- Main loop: 32 jtiles, 2 independent MFMAs per iteration ----
        const uint4* __restrict__ fb = &fbuf[(size_t)(jh * 32) * 64 + lane];
        for (int jt = 0; jt < 32; jt += 2) {
            const bf16x8 a0 = *reinterpret_cast<const bf16x8*>(fb + (size_t)jt * 64);
            const bf16x8 a1 = *reinterpret_cast<const bf16x8*>(fb + (size_t)(jt + 1) * 64);
            f32x16 acc0 = __builtin_amdgcn_mfma_f32_32x32x16_bf16(a0, bfrag, zc, 0, 0, 0);
            f32x16 acc1 = __builtin_amdgcn_mfma_f32_32x32x16_bf16(a1, bfrag, zc, 0, 0, 0);
            FOLD(acc0);
            FOLD(acc1);
        }
        __syncthreads();   // frags fully consumed before restage
    }
#undef FOLD

    // ---- Epilogue: fold mins, merge lane-halves, cross-jh min, distance, sum ----
    float* pmin = reinterpret_cast<float*>(fbuf);   // [2][256], aliases fbuf
    float* ssum = pmin + 512;                       // 4 floats
    {
        float mm = fminf(fminf(m0, m1), fminf(m2, m3));
        mm = fminf(mm, __shfl_xor(mm, 32));
        if (lane < 32)
            pmin[jh * 256 + ig * 32 + (lane & 31)] = mm;
    }
    __syncthreads();
    if (tid < 256) {
        float v = fminf(pmin[tid], pmin[256 + tid]);
        const float ax = src_base[tid * 3 + 0];
        const float ay = src_base[tid * 3 + 1];
        const float az = src_base[tid * 3 + 2];
        const float aa = ax * ax + ay * ay + az * az;
        float d = sqrtf(fmaxf(0.0f, fmaf(2.0f, v, aa)));
        #pragma unroll
        for (int off = 32; off > 0; off >>= 1)
            d += __shfl_down(d, off);
        if ((tid & 63) == 0)
            ssum[tid >> 6] = d;
    }
    __syncthreads();
    if (tid == 0)
        partial[bid] = ssum[0] + ssum[1] + ssum[2] + ssum[3];
}

// Sum 256 block partials, normalize by B*P (gives d1 + d2).
__global__ __launch_bounds__(256) void chamfer_final(
    const float* __restrict__ partial, float* __restrict__ out)
{
    __shared__ float ssum[4];
    const int tid = threadIdx.x;
    float v = partial[tid];
    #pragma unroll
    for (int off = 32; off > 0; off >>= 1)
        v += __shfl_down(v, off);
    if ((tid & 63) == 0)
        ssum[tid >> 6] = v;
    __syncthreads();
    if (tid == 0)
        out[0] = (ssum[0] + ssum[1] + ssum[2] + ssum[3]) * (1.0f / (float)(BB * PP));
}

extern "C" void kernel_launch(void* const* d_in, const int* in_sizes, int n_in,
                              void* d_out, int out_size, void* d_ws, size_t ws_size,
                              hipStream_t stream) {
    const float* y1 = (const float*)d_in[0];
    const float* y2 = (const float*)d_in[1];
    uint4* frags   = (uint4*)d_ws;                          // 2 MB: 16 sets x 8192 uint4
    float* partial = (float*)((char*)d_ws + (1 << 21));     // +256 floats
    float* out     = (float*)d_out;

    build_frags<<<256, 256, 0, stream>>>(y1, y2, frags);
    chamfer_mfma<<<256, 1024, 0, stream>>>(y1, y2, frags, partial);
    chamfer_final<<<1, 256, 0, stream>>>(partial, out);
}

// Round 13
// 17.502 us; speedup vs baseline: 1.3440x; 1.3440x over previous
//
#include <hip/hip_runtime.h>
#include <float.h>
#include <math.h>

#define BB 8
#define PP 4096

typedef __attribute__((ext_vector_type(8))) short bf16x8;
typedef __attribute__((ext_vector_type(16))) float f32x16;

__device__ __forceinline__ unsigned int f2bf(float f) {
    unsigned int u = __float_as_uint(f);
    return (u + 0x7FFFu + ((u >> 16) & 1u)) >> 16;   // RNE bf16
}
__device__ __forceinline__ float bf2f(unsigned int h) {
    return __uint_as_float(h << 16);
}
__device__ __forceinline__ float min3f(float a, float b, float c) {
    return fminf(fminf(a, b), c);                    // fuses to v_min3_f32
}

// One block = (dir, cloud, qgroup of 256 queries) vs all 4096 neighbors.
// MFMA computes t_ji = h_j - a_i.c_j (split-precision bf16 packed into K);
// d^2 = |a|^2 + 2*min_j t.  D[j,i]: col=lane&31 (query), rows over regs/lane-half.
// Wave w owns TWO itiles (2*(w&3), 2*(w&3)+1) and jtile-range (w>>2)*16:
// each A-frag ds_read feeds 2 independent MFMAs (halves LDS traffic vs R9),
// next A-frag prefetched one step ahead.
__global__ __launch_bounds__(1024) void chamfer_mfma(
    const float* __restrict__ y1, const float* __restrict__ y2,
    float* __restrict__ partial)
{
    __shared__ uint4 fbuf[64 * 64];   // 64 KB: A-frags for 64 jtiles (half cloud)

    const int bid   = blockIdx.x;
    const int qg    = bid & 15;
    const int cloud = (bid >> 4) & 7;
    const int dir   = bid >> 7;

    const float* src = (dir == 0) ? y1 : y2;
    const float* tgt = (dir == 0) ? y2 : y1;
    const float* __restrict__ tgt_base = tgt + (size_t)cloud * PP * 3;
    const float* __restrict__ src_base = src + ((size_t)cloud * PP + (size_t)qg * 256) * 3;

    const int tid  = threadIdx.x;
    const int lane = tid & 63;
    const int w    = tid >> 6;
    const int it2  = w & 3;     // itile pair: itiles 2*it2, 2*it2+1
    const int jq   = w >> 2;    // 16-jtile range this wave owns per half

    // ---- Two B-frags (queries), built once in registers ----
    // lane<32 (k0..7):  [nahix,nahiy,nahiz, nalox,naloy,naloz, nahix,nahiy]
    // lane>=32 (k8..15):[nahiz, 1.0, 1.0, 0,0,0,0,0]
    bf16x8 bfragA, bfragB;
    #pragma unroll
    for (int p = 0; p < 2; ++p) {
        const int ql = (2 * it2 + p) * 32 + (lane & 31);
        const float ax = src_base[ql * 3 + 0];
        const float ay = src_base[ql * 3 + 1];
        const float az = src_base[ql * 3 + 2];
        const unsigned int hx = f2bf(-ax), hy = f2bf(-ay), hz = f2bf(-az);
        const unsigned int lx = f2bf(-ax - bf2f(hx));
        const unsigned int ly = f2bf(-ay - bf2f(hy));
        const unsigned int lz = f2bf(-az - bf2f(hz));
        uint4 bb;
        if (lane < 32) {
            bb.x = hx | (hy << 16);
            bb.y = hz | (lx << 16);
            bb.z = ly | (lz << 16);
            bb.w = hx | (hy << 16);
        } else {
            bb.x = hz | (0x3F80u << 16);   // k8 = nahiz, k9 = 1.0
            bb.y = 0x3F80u;                // k10 = 1.0, k11 = 0
            bb.z = 0u;
            bb.w = 0u;
        }
        if (p == 0) bfragA = *reinterpret_cast<bf16x8*>(&bb);
        else        bfragB = *reinterpret_cast<bf16x8*>(&bb);
    }

    float ma0 = FLT_MAX, ma1 = FLT_MAX, ma2 = FLT_MAX, ma3 = FLT_MAX;
    float mb0 = FLT_MAX, mb1 = FLT_MAX, mb2 = FLT_MAX, mb3 = FLT_MAX;

    f32x16 zc;
    #pragma unroll
    for (int r = 0; r < 16; ++r) zc[r] = 0.0f;

#define FOLDA(acc)                                \
    do {                                          \
        ma0 = min3f(ma0, (acc)[0], (acc)[4]);     \
        ma1 = min3f(ma1, (acc)[1], (acc)[5]);     \
        ma2 = min3f(ma2, (acc)[2], (acc)[6]);     \
        ma3 = min3f(ma3, (acc)[3], (acc)[7]);     \
        ma0 = min3f(ma0, (acc)[8], (acc)[12]);    \
        ma1 = min3f(ma1, (acc)[9], (acc)[13]);    \
        ma2 = min3f(ma2, (acc)[10], (acc)[14]);   \
        ma3 = min3f(ma3, (acc)[11], (acc)[15]);   \
    } while (0)
#define FOLDB(acc)                                \
    do {                                          \
        mb0 = min3f(mb0, (acc)[0], (acc)[4]);     \
        mb1 = min3f(mb1, (acc)[1], (acc)[5]);     \
        mb2 = min3f(mb2, (acc)[2], (acc)[6]);     \
        mb3 = min3f(mb3, (acc)[3], (acc)[7]);     \
        mb0 = min3f(mb0, (acc)[8], (acc)[12]);    \
        mb1 = min3f(mb1, (acc)[9], (acc)[13]);    \
        mb2 = min3f(mb2, (acc)[10], (acc)[14]);   \
        mb3 = min3f(mb3, (acc)[11], (acc)[15]);   \
    } while (0)

    for (int half = 0; half < 2; ++half) {
        // ---- Build A-frags for neighbors half*2048 .. +2047 ----
        // A lane<32 (k0..7):  [chix,chiy,chiz, chix,chiy,chiz, clox,cloy]
        // A lane>=32 (k8..15):[cloz, h_hi, h_lo, 0,0,0,0,0]
        #pragma unroll
        for (int rep = 0; rep < 2; ++rep) {
            const int nl = rep * 1024 + tid;            // 0..2047 within half
            const int n  = half * 2048 + nl;
            const float cx = tgt_base[n * 3 + 0];
            const float cy = tgt_base[n * 3 + 1];
            const float cz = tgt_base[n * 3 + 2];
            const unsigned int chx = f2bf(cx), chy = f2bf(cy), chz = f2bf(cz);
            const unsigned int clx = f2bf(cx - bf2f(chx));
            const unsigned int cly = f2bf(cy - bf2f(chy));
            const unsigned int clz = f2bf(cz - bf2f(chz));
            const float hh = 0.5f * (cx * cx + cy * cy + cz * cz);
            const unsigned int hhi = f2bf(hh);
            const unsigned int hlo = f2bf(hh - bf2f(hhi));
            const int tile = nl >> 5, r = nl & 31;
            uint4 lof, hif;
            lof.x = chx | (chy << 16);
            lof.y = chz | (chx << 16);
            lof.z = chy | (chz << 16);
            lof.w = clx | (cly << 16);
            hif.x = clz | (hhi << 16);
            hif.y = hlo;
            hif.z = 0u;
            hif.w = 0u;
            fbuf[tile * 64 + r]      = lof;
            fbuf[tile * 64 + 32 + r] = hif;
        }
        __syncthreads();

        // ---- Main loop: 16 jtiles; per A-read, 2 independent MFMAs ----
        const uint4* __restrict__ fb = &fbuf[(size_t)(jq * 16) * 64 + lane];
        bf16x8 afA = *reinterpret_cast<const bf16x8*>(fb);
        for (int jt = 0; jt < 15; ++jt) {
            const bf16x8 afN =
                *reinterpret_cast<const bf16x8*>(fb + (size_t)(jt + 1) * 64);  // prefetch
            f32x16 acc0 = __builtin_amdgcn_mfma_f32_32x32x16_bf16(afA, bfragA, zc, 0, 0, 0);
            f32x16 acc1 = __builtin_amdgcn_mfma_f32_32x32x16_bf16(afA, bfragB, zc, 0, 0, 0);
            FOLDA(acc0);          // acc1's latency hides under this
            FOLDB(acc1);
            afA = afN;
        }
        {
            f32x16 acc0 = __builtin_amdgcn_mfma_f32_32x32x16_bf16(afA, bfragA, zc, 0, 0, 0);
            f32x16 acc1 = __builtin_amdgcn_mfma_f32_32x32x16_bf16(afA, bfragB, zc, 0, 0, 0);
            FOLDA(acc0);
            FOLDB(acc1);
        }
        __syncthreads();   // frags fully consumed before rebuild / reuse
    }
#undef FOLDA
#undef FOLDB

    // ---- Epilogue: fold mins, merge lane-halves, cross-jq min, distance, sum ----
    float* pmin = reinterpret_cast<float*>(fbuf);   // [4][256], aliases fbuf
    float* ssum = pmin + 1024;                      // 4 floats
    {
        float mmA = fminf(fminf(ma0, ma1), fminf(ma2, ma3));
        mmA = fminf(mmA, __shfl_xor(mmA, 32));
        float mmB = fminf(fminf(mb0, mb1), fminf(mb2, mb3));
        mmB = fminf(mmB, __shfl_xor(mmB, 32));
        if (lane < 32) {
            pmin[jq * 256 + (2 * it2 + 0) * 32 + (lane & 31)] = mmA;
            pmin[jq * 256 + (2 * it2 + 1) * 32 + (lane & 31)] = mmB;
        }
    }
    __syncthreads();
    if (tid < 256) {
        float v = fminf(fminf(pmin[tid], pmin[256 + tid]),
                        fminf(pmin[512 + tid], pmin[768 + tid]));
        const float ax = src_base[tid * 3 + 0];
        const float ay = src_base[tid * 3 + 1];
        const float az = src_base[tid * 3 + 2];
        const float aa = ax * ax + ay * ay + az * az;
        float d = sqrtf(fmaxf(0.0f, fmaf(2.0f, v, aa)));
        #pragma unroll
        for (int off = 32; off > 0; off >>= 1)
            d += __shfl_down(d, off);
        if ((tid & 63) == 0)
            ssum[tid >> 6] = d;
    }
    __syncthreads();
    if (tid == 0)
        partial[bid] = ssum[0] + ssum[1] + ssum[2] + ssum[3];
}

// Sum 256 block partials, normalize by B*P (gives d1 + d2).
__global__ __launch_bounds__(256) void chamfer_final(
    const float* __restrict__ partial, float* __restrict__ out)
{
    __shared__ float ssum[4];
    const int tid = threadIdx.x;
    float v = partial[tid];
    #pragma unroll
    for (int off = 32; off > 0; off >>= 1)
        v += __shfl_down(v, off);
    if ((tid & 63) == 0)
        ssum[tid >> 6] = v;
    __syncthreads();
    if (tid == 0)
        out[0] = (ssum[0] + ssum[1] + ssum[2] + ssum[3]) * (1.0f / (float)(BB * PP));
}

extern "C" void kernel_launch(void* const* d_in, const int* in_sizes, int n_in,
                              void* d_out, int out_size, void* d_ws, size_t ws_size,
                              hipStream_t stream) {
    const float* y1 = (const float*)d_in[0];
    const float* y2 = (const float*)d_in[1];
    float* partial = (float*)d_ws;    // 256 floats of scratch
    float* out     = (float*)d_out;

    chamfer_mfma<<<256, 1024, 0, stream>>>(y1, y2, partial);
    chamfer_final<<<1, 256, 0, stream>>>(partial, out);
}